// Round 6
// baseline (171.259 us; speedup 1.0000x reference)
//
#include <hip/hip_runtime.h>
#include <stdint.h>

// Problem constants
#define B_   4
#define P_   20000
#define NB_  9
#define WN_  17
#define CI_  64
#define CO_  128
#define PTS  32            // points per block -> 128 GEMM rows (4 batches x 32 pts)
#define NBLK (P_ / PTS)    // 625 blocks

typedef __fp16 f16x8 __attribute__((ext_vector_type(8)));
typedef __fp16 h2    __attribute__((ext_vector_type(2)));
typedef float  f32x16 __attribute__((ext_vector_type(16)));

union H2U { h2 h; uint32_t u; };
union F8U { f16x8 v; h2 h[4]; uint4 u; };

// LDS image layout for one B chunk (128 co x 32 k, f16):
// row-pair layout: entry(co, oloc) at ushort index (co>>1)*64 + slot(co,oloc)*8
// slot = (co&1) | ((oloc ^ ((co>>1)&3)) << 1)  -- 8 consecutive lanes hit 8
// distinct 16B slots -> conflict-free ds_read_b128 / writes.
__device__ __forceinline__ int b_idx(int co, int oloc) {
    int slot = (co & 1) | (((oloc ^ ((co >> 1) & 3)) & 3) << 1);
    return (co >> 1) * 64 + slot * 8;
}

// prep: Wm fp32 -> f16, stored as the exact LDS chunk image per (m, pass).
// wsb ushort index = (m*2+pass)*4096 + b_idx(co, oloc) + j
__global__ void prep_wm(const float* __restrict__ w, ushort* __restrict__ wsb) {
    int i = blockIdx.x * 256 + threadIdx.x;   // granule id: 17*2*512 = 17408
    int m  = i >> 10;                         // 1024 granules per m
    int r  = i & 1023;
    int p  = r >> 9;                          // pass (0,1)
    int rr = r & 511;
    int co = rr >> 2, oloc = rr & 3;
    const float* src = w + (size_t)m * (CO_ * CI_) + co * CI_ + (p * 4 + oloc) * 8;
    float4 v0 = *(const float4*)(src);
    float4 v1 = *(const float4*)(src + 4);
    F8U h;
    h.h[0] = __builtin_amdgcn_cvt_pkrtz(v0.x, v0.y);
    h.h[1] = __builtin_amdgcn_cvt_pkrtz(v0.z, v0.w);
    h.h[2] = __builtin_amdgcn_cvt_pkrtz(v1.x, v1.y);
    h.h[3] = __builtin_amdgcn_cvt_pkrtz(v1.z, v1.w);
    *(uint4*)&wsb[(m * 2 + p) * 4096 + b_idx(co, oloc)] = h.u;
}

template <bool PRE>
__global__ __launch_bounds__(256, 2)
void lasm_fused(const float* __restrict__ in_pc,    // (B,P,CI)    f32
                const float* __restrict__ raw_w,    // (P,NB,WN)   f32
                const float* __restrict__ weights,  // (WN,CO*CI)  f32
                const float* __restrict__ bias,     // (P,CO)      f32
                const int*   __restrict__ nbr,      // (P,NB)      int32
                const ushort* __restrict__ wsb,     // pre-swizzled f16 chunks
                float*       __restrict__ out)      // (B,P,CO)    f32
{
    __shared__ __align__(16) int      s_nid[PTS * NB_];        // [pl*9+n]
    __shared__ __align__(16) uint32_t s_w2[WN_ * NB_ * 33];    // [(m*9+n)*33+pl], h2-splat
    __shared__ __align__(16) ushort   s_b[2][4096];            // B chunk dbuf (8 KB each)

    const int tid  = threadIdx.x;
    const int lane = tid & 63;
    const int w    = tid >> 6;        // wave = batch index (4 waves)
    const int arow = lane & 31;       // MFMA row / point-local index
    const int q    = lane >> 5;       // k-half
    const int p0   = blockIdx.x * PTS;

    // ---- neighbor ids (flat layout matches global). 288 > 256: stride loop! ----
    for (int t = tid; t < PTS * NB_; t += 256) s_nid[t] = nbr[p0 * NB_ + t];
    // ---- w staging: coalesced global read, h2-splat, pl-padded (33) layout ----
    for (int idx = tid; idx < PTS * NB_ * WN_; idx += 256) {
        int pl  = idx / (NB_ * WN_);
        int rem = idx % (NB_ * WN_);
        int n   = rem / WN_;
        int m   = rem % WN_;
        float wf = raw_w[(size_t)p0 * NB_ * WN_ + idx];
        H2U c; c.h = __builtin_amdgcn_cvt_pkrtz(wf, wf);
        s_w2[(m * NB_ + n) * 33 + pl] = c.u;
    }
    __syncthreads();

    f32x16 acc[4];
    #pragma unroll
    for (int c = 0; c < 4; ++c)
        #pragma unroll
        for (int j = 0; j < 16; ++j) acc[c][j] = 0.f;

    const size_t binpc = (size_t)w * P_ * CI_;

    auto stage_b = [&](int pass, int m, int buf) {
        if (PRE) {
            #pragma unroll
            for (int j = 0; j < 2; ++j) {
                int flat = j * 256 + tid;             // 512 granules per chunk
                uint4 v = *(const uint4*)&wsb[(size_t)(m * 2 + pass) * 4096 + flat * 8];
                *(uint4*)&s_b[buf][flat * 8] = v;
            }
        } else {
            #pragma unroll
            for (int j = 0; j < 2; ++j) {
                int flat = j * 256 + tid;
                int co = flat >> 2, oloc = flat & 3;
                const float* src = weights + (size_t)m * (CO_ * CI_) + co * CI_ + (pass * 4 + oloc) * 8;
                float4 v0 = *(const float4*)(src);
                float4 v1 = *(const float4*)(src + 4);
                F8U h;
                h.h[0] = __builtin_amdgcn_cvt_pkrtz(v0.x, v0.y);
                h.h[1] = __builtin_amdgcn_cvt_pkrtz(v0.z, v0.w);
                h.h[2] = __builtin_amdgcn_cvt_pkrtz(v1.x, v1.y);
                h.h[3] = __builtin_amdgcn_cvt_pkrtz(v1.z, v1.w);
                *(uint4*)&s_b[buf][b_idx(co, oloc)] = h.u;
            }
        }
    };

    for (int pass = 0; pass < 2; ++pass) {
        // ---- gather x for this pass's k-octs: floats ch0.. and ch0+16.. ----
        h2 x[NB_][8];
        const int ch0 = pass * 32 + q * 8;     // first oct's float offset
        #pragma unroll
        for (int n = 0; n < NB_; ++n) {
            uint32_t nid = (uint32_t)s_nid[arow * NB_ + n];
            if (nid < (uint32_t)P_) {
                const float* src = in_pc + binpc + (size_t)nid * CI_ + ch0;
                float4 a0 = *(const float4*)(src);
                float4 a1 = *(const float4*)(src + 4);
                float4 b0 = *(const float4*)(src + 16);   // oct +2 (16 floats on)
                float4 b1 = *(const float4*)(src + 20);
                x[n][0] = __builtin_amdgcn_cvt_pkrtz(a0.x, a0.y);
                x[n][1] = __builtin_amdgcn_cvt_pkrtz(a0.z, a0.w);
                x[n][2] = __builtin_amdgcn_cvt_pkrtz(a1.x, a1.y);
                x[n][3] = __builtin_amdgcn_cvt_pkrtz(a1.z, a1.w);
                x[n][4] = __builtin_amdgcn_cvt_pkrtz(b0.x, b0.y);
                x[n][5] = __builtin_amdgcn_cvt_pkrtz(b0.z, b0.w);
                x[n][6] = __builtin_amdgcn_cvt_pkrtz(b1.x, b1.y);
                x[n][7] = __builtin_amdgcn_cvt_pkrtz(b1.z, b1.w);
            } else {
                h2 z = {(__fp16)0.f, (__fp16)0.f};
                #pragma unroll
                for (int j = 0; j < 8; ++j) x[n][j] = z;
            }
        }

        stage_b(pass, 0, 0);
        __syncthreads();

        int cur = 0;
        for (int m = 0; m < WN_; ++m) {
            int nxt = cur ^ 1;
            if (m + 1 < WN_) stage_b(pass, m + 1, nxt);

            // ---- per-lane w for its point ----
            H2U wc[9];
            #pragma unroll
            for (int n = 0; n < NB_; ++n) wc[n].u = s_w2[(m * NB_ + n) * 33 + arow];

            // ---- stage-1 in registers: fuse[row=arow][k-octs of this pass] ----
            F8U f[2];
            #pragma unroll
            for (int kk = 0; kk < 2; ++kk) {
                #pragma unroll
                for (int r4 = 0; r4 < 4; ++r4) {
                    h2 c = {(__fp16)0.f, (__fp16)0.f};
                    #pragma unroll
                    for (int n = 0; n < NB_; ++n) c += wc[n].h * x[n][kk * 4 + r4];
                    f[kk].h[r4] = c;
                }
            }

            // ---- MFMA: A from registers, B from LDS ----
            #pragma unroll
            for (int kk = 0; kk < 2; ++kk) {
                int oloc = kk * 2 + q;
                #pragma unroll
                for (int c = 0; c < 4; ++c) {
                    int bco = c * 32 + arow;
                    f16x8 bf = *(const f16x8*)&s_b[cur][b_idx(bco, oloc)];
                    acc[c] = __builtin_amdgcn_mfma_f32_32x32x16_f16(f[kk].v, bf, acc[c], 0, 0, 0);
                }
            }
            __syncthreads();
            cur = nxt;
        }
    }

    // ---- epilogue: bias + ELU + fp32 store ----
    #pragma unroll
    for (int c = 0; c < 4; ++c) {
        int col = c * 32 + arow;
        #pragma unroll
        for (int v = 0; v < 16; ++v) {
            int lr = (v & 3) + 8 * (v >> 2) + 4 * q;   // local point 0..31
            int p  = p0 + lr;
            float val = acc[c][v] + bias[(size_t)p * CO_ + col];
            val = (val > 0.f) ? val : (__expf(val) - 1.f);
            out[((size_t)w * P_ + p) * CO_ + col] = val;
        }
    }
}

extern "C" void kernel_launch(void* const* d_in, const int* in_sizes, int n_in,
                              void* d_out, int out_size, void* d_ws, size_t ws_size,
                              hipStream_t stream) {
    const float* in_pc   = (const float*)d_in[0];
    const float* raw_w   = (const float*)d_in[1];
    const float* weights = (const float*)d_in[2];
    const float* bias    = (const float*)d_in[3];
    const int*   nbr     = (const int*)  d_in[4];
    float* out = (float*)d_out;

    const size_t need = (size_t)WN_ * 2 * 4096 * sizeof(ushort);   // 278,528 B
    if (d_ws != nullptr && ws_size >= need) {
        ushort* wsb = (ushort*)d_ws;
        prep_wm<<<dim3(WN_ * 2 * 512 / 256), dim3(256), 0, stream>>>(weights, wsb);
        lasm_fused<true><<<dim3(NBLK), dim3(256), 0, stream>>>(
            in_pc, raw_w, weights, bias, nbr, wsb, out);
    } else {
        lasm_fused<false><<<dim3(NBLK), dim3(256), 0, stream>>>(
            in_pc, raw_w, weights, bias, nbr, nullptr, out);
    }
}

// Round 7
// 164.072 us; speedup vs baseline: 1.0438x; 1.0438x over previous
//
#include <hip/hip_runtime.h>
#include <stdint.h>

// Problem constants
#define B_   4
#define P_   20000
#define NB_  9
#define WN_  17
#define CI_  64
#define CO_  128
#define PTS  16            // points per block -> 64 rows = 2 M-tiles of 32
#define NBLK (P_ / PTS)    // 1250 blocks

typedef __fp16 f16x8 __attribute__((ext_vector_type(8)));
typedef __fp16 h2    __attribute__((ext_vector_type(2)));
typedef float  f32x16 __attribute__((ext_vector_type(16)));

union H2U { h2 h; uint32_t u; };
union F8U { f16x8 v; h2 h[4]; uint4 u; };

// wsb granule (16B = 8 f16) index: (((m*2+pass)*4 + oloc)*128 + co)*8 ushorts.
// Consecutive co are contiguous -> a wave's 32-lane fragment load is 512B dense.
__global__ void prep_wm(const float* __restrict__ w, ushort* __restrict__ wsb) {
    int i = blockIdx.x * 256 + threadIdx.x;     // 0 .. 17407 (17*2*4*128)
    int m2p  = i >> 9;                          // m*2+pass
    int r    = i & 511;
    int oloc = r >> 7, co = r & 127;
    int m = m2p >> 1, p = m2p & 1;
    const float* src = w + (size_t)m * (CO_ * CI_) + co * CI_ + (p * 4 + oloc) * 8;
    float4 v0 = *(const float4*)(src);
    float4 v1 = *(const float4*)(src + 4);
    F8U h;
    h.h[0] = __builtin_amdgcn_cvt_pkrtz(v0.x, v0.y);
    h.h[1] = __builtin_amdgcn_cvt_pkrtz(v0.z, v0.w);
    h.h[2] = __builtin_amdgcn_cvt_pkrtz(v1.x, v1.y);
    h.h[3] = __builtin_amdgcn_cvt_pkrtz(v1.z, v1.w);
    *(uint4*)&wsb[(size_t)((m2p * 4 + oloc) * 128 + co) * 8] = h.u;
}

template <bool PRE>
__global__ __launch_bounds__(256, 3)
void lasm_fused(const float* __restrict__ in_pc,    // (B,P,CI)    f32
                const float* __restrict__ raw_w,    // (P,NB,WN)   f32
                const float* __restrict__ weights,  // (WN,CO*CI)  f32
                const float* __restrict__ bias,     // (P,CO)      f32
                const int*   __restrict__ nbr,      // (P,NB)      int32
                const ushort* __restrict__ wsb,     // pre-swizzled f16 panel
                float*       __restrict__ out)      // (B,P,CO)    f32
{
    __shared__ __align__(16) int      s_nid[PTS * NB_];      // 144 ints
    __shared__ __align__(16) uint32_t s_w2[WN_ * NB_ * 17];  // [(m*9+n)*17+pl], ~10.2 KB

    const int tid  = threadIdx.x;
    const int lane = tid & 63;
    const int wv   = tid >> 6;
    const int arow = lane & 31;       // row within M-tile / co within co-tile
    const int q    = lane >> 5;       // k-half
    const int mt   = wv >> 1;         // M-tile: rows mt*32 .. mt*32+31
    const int ch   = wv & 1;          // co half: cols ch*64 .. ch*64+63
    const int p0   = blockIdx.x * PTS;

    // ---- prologue staging (the ONLY barrier in the kernel) ----
    if (tid < PTS * NB_) s_nid[tid] = nbr[p0 * NB_ + tid];
    for (int idx = tid; idx < PTS * NB_ * WN_; idx += 256) {
        int pl2 = idx / (NB_ * WN_);
        int rem = idx % (NB_ * WN_);
        int n   = rem / WN_;
        int m   = rem % WN_;
        float wf = raw_w[(size_t)p0 * NB_ * WN_ + idx];
        H2U c; c.h = __builtin_amdgcn_cvt_pkrtz(wf, wf);
        s_w2[(m * NB_ + n) * 17 + pl2] = c.u;
    }
    __syncthreads();

    f32x16 acc[2];
    #pragma unroll
    for (int c = 0; c < 2; ++c)
        #pragma unroll
        for (int j = 0; j < 16; ++j) acc[c][j] = 0.f;

    const int brow = mt * 2 + (arow >> 4);    // batch of this lane's row
    const int pl   = arow & 15;               // point-local index
    const size_t binpc = (size_t)brow * P_ * CI_;

    // B-fragment load, direct global->VGPR (L2-resident panel, no LDS, no barrier)
    auto load_b = [&](int m, int pass, int kk, int c) -> f16x8 {
        int oloc = kk * 2 + q;
        if (PRE) {
            F8U r;
            r.u = *(const uint4*)&wsb[(size_t)(((m * 2 + pass) * 4 + oloc) * 128
                                               + ch * 64 + c * 32 + arow) * 8];
            return r.v;
        } else {
            const float* s = weights + (size_t)m * (CO_ * CI_)
                           + (ch * 64 + c * 32 + arow) * CI_ + (pass * 4 + oloc) * 8;
            float4 v0 = *(const float4*)(s);
            float4 v1 = *(const float4*)(s + 4);
            F8U r;
            r.h[0] = __builtin_amdgcn_cvt_pkrtz(v0.x, v0.y);
            r.h[1] = __builtin_amdgcn_cvt_pkrtz(v0.z, v0.w);
            r.h[2] = __builtin_amdgcn_cvt_pkrtz(v1.x, v1.y);
            r.h[3] = __builtin_amdgcn_cvt_pkrtz(v1.z, v1.w);
            return r.v;
        }
    };

    for (int pass = 0; pass < 2; ++pass) {
        // ---- gather x for this pass's k-octs (held in registers) ----
        h2 x[NB_][8];
        const int ch0 = pass * 32 + q * 8;
        #pragma unroll
        for (int n = 0; n < NB_; ++n) {
            uint32_t nid = (uint32_t)s_nid[pl * NB_ + n];
            if (nid < (uint32_t)P_) {
                const float* src = in_pc + binpc + (size_t)nid * CI_ + ch0;
                float4 a0 = *(const float4*)(src);
                float4 a1 = *(const float4*)(src + 4);
                float4 b0 = *(const float4*)(src + 16);
                float4 b1 = *(const float4*)(src + 20);
                x[n][0] = __builtin_amdgcn_cvt_pkrtz(a0.x, a0.y);
                x[n][1] = __builtin_amdgcn_cvt_pkrtz(a0.z, a0.w);
                x[n][2] = __builtin_amdgcn_cvt_pkrtz(a1.x, a1.y);
                x[n][3] = __builtin_amdgcn_cvt_pkrtz(a1.z, a1.w);
                x[n][4] = __builtin_amdgcn_cvt_pkrtz(b0.x, b0.y);
                x[n][5] = __builtin_amdgcn_cvt_pkrtz(b0.z, b0.w);
                x[n][6] = __builtin_amdgcn_cvt_pkrtz(b1.x, b1.y);
                x[n][7] = __builtin_amdgcn_cvt_pkrtz(b1.z, b1.w);
            } else {
                h2 z = {(__fp16)0.f, (__fp16)0.f};
                #pragma unroll
                for (int j = 0; j < 8; ++j) x[n][j] = z;
            }
        }

        // ---- software-pipelined, barrier-free m-loop ----
        f16x8 bA0 = load_b(0, pass, 0, 0);
        f16x8 bA1 = load_b(0, pass, 0, 1);

        for (int m = 0; m < WN_; ++m) {
            // per-lane w for its point
            H2U wc[9];
            #pragma unroll
            for (int n = 0; n < NB_; ++n) wc[n].u = s_w2[(m * NB_ + n) * 17 + pl];

            // stage-1 in registers: fuse[row=arow][this pass's 4 octs]
            F8U f[2];
            #pragma unroll
            for (int kk = 0; kk < 2; ++kk) {
                #pragma unroll
                for (int r4 = 0; r4 < 4; ++r4) {
                    h2 c = {(__fp16)0.f, (__fp16)0.f};
                    #pragma unroll
                    for (int n = 0; n < NB_; ++n) c += wc[n].h * x[n][kk * 4 + r4];
                    f[kk].h[r4] = c;
                }
            }

            f16x8 bB0 = load_b(m, pass, 1, 0);
            f16x8 bB1 = load_b(m, pass, 1, 1);
            acc[0] = __builtin_amdgcn_mfma_f32_32x32x16_f16(f[0].v, bA0, acc[0], 0, 0, 0);
            acc[1] = __builtin_amdgcn_mfma_f32_32x32x16_f16(f[0].v, bA1, acc[1], 0, 0, 0);

            int mn = (m + 1 < WN_) ? m + 1 : m;       // clamped prefetch (stays in-bounds)
            f16x8 nA0 = load_b(mn, pass, 0, 0);
            f16x8 nA1 = load_b(mn, pass, 0, 1);
            acc[0] = __builtin_amdgcn_mfma_f32_32x32x16_f16(f[1].v, bB0, acc[0], 0, 0, 0);
            acc[1] = __builtin_amdgcn_mfma_f32_32x32x16_f16(f[1].v, bB1, acc[1], 0, 0, 0);
            bA0 = nA0; bA1 = nA1;
        }
    }

    // ---- epilogue: bias + ELU + nontemporal fp32 store ----
    #pragma unroll
    for (int c = 0; c < 2; ++c) {
        int col = ch * 64 + c * 32 + arow;
        #pragma unroll
        for (int v = 0; v < 16; ++v) {
            int lr = (v & 3) + 8 * (v >> 2) + 4 * q;   // local row 0..31 in M-tile
            int b  = mt * 2 + (lr >> 4);
            int p  = p0 + (lr & 15);
            float val = acc[c][v] + bias[(size_t)p * CO_ + col];
            val = (val > 0.f) ? val : (__expf(val) - 1.f);
            __builtin_nontemporal_store(val, &out[((size_t)b * P_ + p) * CO_ + col]);
        }
    }
}

extern "C" void kernel_launch(void* const* d_in, const int* in_sizes, int n_in,
                              void* d_out, int out_size, void* d_ws, size_t ws_size,
                              hipStream_t stream) {
    const float* in_pc   = (const float*)d_in[0];
    const float* raw_w   = (const float*)d_in[1];
    const float* weights = (const float*)d_in[2];
    const float* bias    = (const float*)d_in[3];
    const int*   nbr     = (const int*)  d_in[4];
    float* out = (float*)d_out;

    const size_t need = (size_t)WN_ * 2 * 4096 * sizeof(ushort);   // 278,528 B
    if (d_ws != nullptr && ws_size >= need) {
        ushort* wsb = (ushort*)d_ws;
        prep_wm<<<dim3(WN_ * 2 * 512 / 256), dim3(256), 0, stream>>>(weights, wsb);
        lasm_fused<true><<<dim3(NBLK), dim3(256), 0, stream>>>(
            in_pc, raw_w, weights, bias, nbr, wsb, out);
    } else {
        lasm_fused<false><<<dim3(NBLK), dim3(256), 0, stream>>>(
            in_pc, raw_w, weights, bias, nbr, nullptr, out);
    }
}